// Round 4
// baseline (84.730 us; speedup 1.0000x reference)
//
#include <hip/hip_runtime.h>
#include <math.h>

#define NF 1024
#define DIM 256
#define BATCH 2048
#define K 512            // interleaved (x^2, x) -> 2*DIM
#define BM 64
#define BN 64
#define NCHUNK (NF / BN) // 16

// ws layout (16B aligned):
//   [0, 2MB)    : Ab bf16[BATCH][K]  rows: (x^2, x) interleaved per dim
//   [2MB, 3MB)  : Bb bf16[NF][K]     rows: (s2, -2*s2*mu) interleaved per dim
//   [3MB, +4KB) : c  float[NF]
//   then        : rowPartial float[NCHUNK][BATCH] (fully overwritten)
#define WS_A_BYTES (BATCH * K * 2)
#define WS_B_OFF   WS_A_BYTES
#define WS_C_OFF   (WS_A_BYTES + NF * K * 2)
#define WS_RP_OFF  (WS_C_OFF + NF * 4)

typedef __attribute__((ext_vector_type(8))) short short8;   // 8 bf16
typedef __attribute__((ext_vector_type(4))) float f32x4;    // MFMA acc

__device__ __forceinline__ unsigned short f2bf(float f) {
    unsigned u = __float_as_uint(f);
    u += 0x7fffu + ((u >> 16) & 1u);       // RNE
    return (unsigned short)(u >> 16);
}

__device__ __forceinline__ void gl_lds16(const ushort* g, ushort* l) {
    __builtin_amdgcn_global_load_lds(
        (const __attribute__((address_space(1))) void*)g,
        (__attribute__((address_space(3))) void*)l, 16, 0, 0);
}

// ---------------------------------------------------------------------------
// K1: blocks [0,NF): formula f -> Bb row (coalesced u32 stores) + c[f].
//     blocks [NF, NF+BATCH*DIM/256): pack x -> Ab.
__global__ __launch_bounds__(256) void k_prep(const float* __restrict__ mu,
                                              const float* __restrict__ sigma,
                                              const float* __restrict__ x,
                                              unsigned int* __restrict__ Ab32,
                                              unsigned int* __restrict__ Bb32,
                                              float* __restrict__ c) {
    const int t = threadIdx.x;
    if (blockIdx.x >= NF) {
        const int i = (blockIdx.x - NF) * 256 + t;
        const float v = x[i];
        Ab32[i] = (unsigned)f2bf(v * v) | ((unsigned)f2bf(v) << 16);
        return;
    }
    const int f = blockIdx.x;
    const float m = mu[f * DIM + t];
    const float s = sigma[f * DIM + t];
    const float s2 = s * s;
    Bb32[f * DIM + t] = (unsigned)f2bf(s2) | ((unsigned)f2bf(-2.0f * s2 * m) << 16);

    float cp = s2 * m * m;
    #pragma unroll
    for (int off = 32; off > 0; off >>= 1) cp += __shfl_down(cp, off, 64);
    __shared__ float red[4];
    const int lane = t & 63, wv = t >> 6;
    if (lane == 0) red[wv] = cp;
    __syncthreads();
    if (t == 0) c[f] = red[0] + red[1] + red[2] + red[3];
}

// ---------------------------------------------------------------------------
// K2: bf16 MFMA GEMM + exp epilogue. Grid (32,16)=512 blocks, 4 waves (2x2).
// Whole 64x512 A tile staged ONCE via 16 global_load_lds + ONE barrier;
// K-loop is barrier-free: A fragments from LDS (XOR-swizzled slots, 2-way
// banks = free), B fragments global->VGPR (compiler pipelines with vmcnt(N)
// -- no vmcnt(0) drains in the loop).
__global__ __launch_bounds__(256, 2) void k_main(const ushort* __restrict__ Ab,
                                                 const ushort* __restrict__ Bb,
                                                 const float* __restrict__ c,
                                                 const float* __restrict__ temp,
                                                 float* __restrict__ out,
                                                 float* __restrict__ rowPartial) {
    const int t = threadIdx.x;
    const int w = t >> 6;
    const int lane = t & 63;
    const int m16 = lane & 15;
    const int q = lane >> 4;
    const int wr = w >> 1, wc = w & 1;
    const int r0 = blockIdx.x * BM;
    const int n0 = blockIdx.y * BN;

    __shared__ __align__(16) ushort Alds[BM * K];   // 64 KB
    __shared__ float sums[4][32];

    // stage whole A tile: 16 insts x 256 lanes x 16B = 64 KB.
    // dest 16B-slot s: row = s>>6, phys kc' = s&63; fetch logical
    // kc = (kc'&56) | ((kc'&7) ^ (row&7))  (xor involution).
    #pragma unroll
    for (int i = 0; i < 16; ++i) {
        const int s = i * 256 + t;
        const int row = s >> 6;
        const int kcp = s & 63;
        const int kcl = (kcp & 56) | ((kcp & 7) ^ (row & 7));
        gl_lds16(Ab + (r0 + row) * K + kcl * 8, &Alds[s * 8]);
    }

    f32x4 acc[2][2];
    #pragma unroll
    for (int rt = 0; rt < 2; ++rt)
        #pragma unroll
        for (int ct = 0; ct < 2; ++ct) acc[rt][ct] = (f32x4){0.f, 0.f, 0.f, 0.f};

    const ushort* __restrict__ Brow0 = Bb + (n0 + wc * 32 + m16) * K;
    const ushort* __restrict__ Brow1 = Brow0 + 16 * K;

    __syncthreads();    // single drain of the A stage

    #pragma unroll
    for (int ks = 0; ks < K; ks += 32) {
        const int kcq = (ks >> 3) + q;
        short8 av[2], bv[2];
        bv[0] = *(const short8*)&Brow0[ks + q * 8];
        bv[1] = *(const short8*)&Brow1[ks + q * 8];
        #pragma unroll
        for (int j = 0; j < 2; ++j) {
            const int ar = wr * 32 + j * 16 + m16;
            const int slot = (kcq & 56) | ((kcq & 7) ^ (ar & 7));
            av[j] = *(const short8*)&Alds[ar * K + slot * 8];
        }
        #pragma unroll
        for (int rt = 0; rt < 2; ++rt)
            #pragma unroll
            for (int ct = 0; ct < 2; ++ct)
                acc[rt][ct] = __builtin_amdgcn_mfma_f32_16x16x32_bf16(
                    av[rt], bv[ct], acc[rt][ct], 0, 0, 0);
    }

    // epilogue: dist2 -> p = exp(g*exp(-dist)); store + deterministic partials
    const float g = 1.0f / (1.0f + __expf(-temp[0]));
    #pragma unroll
    for (int rt = 0; rt < 2; ++rt) {
        float s[4] = {0.f, 0.f, 0.f, 0.f};
        #pragma unroll
        for (int ct = 0; ct < 2; ++ct) {
            const int fcol = n0 + wc * 32 + ct * 16 + m16;
            const float cn = c[fcol];
            #pragma unroll
            for (int i = 0; i < 4; ++i) {
                const float dist2 = acc[rt][ct][i] + cn;
                const float dist = sqrtf(fmaxf(dist2, 0.0f));
                const float p = __expf(g * __expf(-dist));
                const int row = r0 + wr * 32 + rt * 16 + q * 4 + i;
                out[row * NF + fcol] = p;
                s[i] += p;
            }
        }
        #pragma unroll
        for (int i = 0; i < 4; ++i) {
            #pragma unroll
            for (int mask = 1; mask < 16; mask <<= 1)
                s[i] += __shfl_xor(s[i], mask, 64);
        }
        if (m16 == 0) {
            #pragma unroll
            for (int i = 0; i < 4; ++i) sums[w][rt * 16 + q * 4 + i] = s[i];
        }
    }
    __syncthreads();
    if (t < BM) {
        const int half = t >> 5, lr = t & 31;
        rowPartial[blockIdx.y * BATCH + r0 + t] =
            sums[half * 2][lr] + sums[half * 2 + 1][lr];
    }
}

// ---------------------------------------------------------------------------
// K3: block = one batch row; normalize by the 16 chunk-sums.
__global__ __launch_bounds__(256) void k_norm(float* __restrict__ out,
                                              const float* __restrict__ rowPartial) {
    const int row = blockIdx.x;
    float ssum = 0.0f;
    #pragma unroll
    for (int ch = 0; ch < NCHUNK; ++ch) ssum += rowPartial[ch * BATCH + row];
    const float inv = 1.0f / ssum;
    float4* o4 = (float4*)(out + row * NF);
    float4 v = o4[threadIdx.x];
    v.x *= inv; v.y *= inv; v.z *= inv; v.w *= inv;
    o4[threadIdx.x] = v;
}

extern "C" void kernel_launch(void* const* d_in, const int* in_sizes, int n_in,
                              void* d_out, int out_size, void* d_ws, size_t ws_size,
                              hipStream_t stream) {
    const float* x     = (const float*)d_in[0];
    const float* mu    = (const float*)d_in[1];
    const float* sigma = (const float*)d_in[2];
    const float* temp  = (const float*)d_in[3];
    float* out = (float*)d_out;

    char* ws = (char*)d_ws;
    ushort* Ab        = (ushort*)ws;
    ushort* Bb        = (ushort*)(ws + WS_B_OFF);
    float*  c         = (float*)(ws + WS_C_OFF);
    float*  rowPartial = (float*)(ws + WS_RP_OFF);

    k_prep<<<NF + BATCH * DIM / 256, 256, 0, stream>>>(mu, sigma, x,
                                                       (unsigned int*)Ab,
                                                       (unsigned int*)Bb, c);

    dim3 g2(BATCH / BM, NF / BN);
    k_main<<<g2, 256, 0, stream>>>(Ab, Bb, c, temp, out, rowPartial);

    k_norm<<<BATCH, 256, 0, stream>>>(out, rowPartial);
}

// Round 5
// 84.708 us; speedup vs baseline: 1.0003x; 1.0003x over previous
//
#include <hip/hip_runtime.h>
#include <math.h>

#define NF 1024
#define DIM 256
#define BATCH 2048
#define K 512            // interleaved (x^2, x) -> 2*DIM
#define BM 64
#define BN 64
#define NCHUNK (NF / BN) // 16

// ws layout (16B aligned):
//   [0, 2MB)    : Ab bf16[BATCH][K]  rows: (x^2, x) interleaved per dim
//   [2MB, 3MB)  : Bb bf16[NF][K]     rows: (s2, -2*s2*mu) interleaved per dim
//   [3MB, +4KB) : c  float[NF]
//   then        : rowPartial float[NCHUNK][BATCH] (fully overwritten)
#define WS_A_BYTES (BATCH * K * 2)
#define WS_B_OFF   WS_A_BYTES
#define WS_C_OFF   (WS_A_BYTES + NF * K * 2)
#define WS_RP_OFF  (WS_C_OFF + NF * 4)

typedef __attribute__((ext_vector_type(8))) short short8;   // 8 bf16
typedef __attribute__((ext_vector_type(4))) float f32x4;    // MFMA acc

__device__ __forceinline__ unsigned short f2bf(float f) {
    unsigned u = __float_as_uint(f);
    u += 0x7fffu + ((u >> 16) & 1u);       // RNE
    return (unsigned short)(u >> 16);
}

__device__ __forceinline__ void gl_lds16(const ushort* g, ushort* l) {
    __builtin_amdgcn_global_load_lds(
        (const __attribute__((address_space(1))) void*)g,
        (__attribute__((address_space(3))) void*)l, 16, 0, 0);
}

// ---------------------------------------------------------------------------
// K1: blocks [0,NF): formula f -> Bb row (coalesced u32 stores) + c[f].
//     blocks [NF, NF+BATCH*DIM/256): pack x -> Ab.
__global__ __launch_bounds__(256) void k_prep(const float* __restrict__ mu,
                                              const float* __restrict__ sigma,
                                              const float* __restrict__ x,
                                              unsigned int* __restrict__ Ab32,
                                              unsigned int* __restrict__ Bb32,
                                              float* __restrict__ c) {
    const int t = threadIdx.x;
    if (blockIdx.x >= NF) {
        const int i = (blockIdx.x - NF) * 256 + t;
        const float v = x[i];
        Ab32[i] = (unsigned)f2bf(v * v) | ((unsigned)f2bf(v) << 16);
        return;
    }
    const int f = blockIdx.x;
    const float m = mu[f * DIM + t];
    const float s = sigma[f * DIM + t];
    const float s2 = s * s;
    Bb32[f * DIM + t] = (unsigned)f2bf(s2) | ((unsigned)f2bf(-2.0f * s2 * m) << 16);

    float cp = s2 * m * m;
    #pragma unroll
    for (int off = 32; off > 0; off >>= 1) cp += __shfl_down(cp, off, 64);
    __shared__ float red[4];
    const int lane = t & 63, wv = t >> 6;
    if (lane == 0) red[wv] = cp;
    __syncthreads();
    if (t == 0) c[f] = red[0] + red[1] + red[2] + red[3];
}

// ---------------------------------------------------------------------------
// K2: bf16 MFMA GEMM + exp epilogue. 1-D grid of 512 blocks, 4 waves (2x2).
// XCD-aware mapping: blockIdx%8 = XCD (round-robin dispatch heuristic);
// each XCD gets 4 row-blocks x all 16 col-chunks -> its working set
// (A-slice 256KB + full B 1MB) fits the per-XCD 4MiB L2, collapsing the
// ~100MB of cross-XCD/L3 re-read traffic (the r2-r4 invariant) to ~10MB.
// Body: whole 64x512 A tile staged ONCE via global_load_lds + one barrier;
// barrier-free K-loop, A from LDS (XOR-swizzled, 2-way banks = free),
// B global->VGPR (compiler pipelines with vmcnt(N), now L2-hit).
__global__ __launch_bounds__(256, 2) void k_main(const ushort* __restrict__ Ab,
                                                 const ushort* __restrict__ Bb,
                                                 const float* __restrict__ c,
                                                 const float* __restrict__ temp,
                                                 float* __restrict__ out,
                                                 float* __restrict__ rowPartial) {
    const int t = threadIdx.x;
    const int w = t >> 6;
    const int lane = t & 63;
    const int m16 = lane & 15;
    const int q = lane >> 4;
    const int wr = w >> 1, wc = w & 1;

    // XCD-aware block -> (row-block, col-chunk)
    const int bid = blockIdx.x;          // 0..511
    const int xcd = bid & 7;
    const int j = bid >> 3;              // 0..63
    const int nc = j & 15;
    const int rb = xcd * 4 + (j >> 4);   // 0..31
    const int r0 = rb * BM;
    const int n0 = nc * BN;

    __shared__ __align__(16) ushort Alds[BM * K];   // 64 KB
    __shared__ float sums[4][32];

    // stage whole A tile: 16 insts x 256 lanes x 16B = 64 KB.
    // dest 16B-slot s: row = s>>6, phys kc' = s&63; fetch logical
    // kc = (kc'&56) | ((kc'&7) ^ (row&7))  (xor involution).
    #pragma unroll
    for (int i = 0; i < 16; ++i) {
        const int s = i * 256 + t;
        const int row = s >> 6;
        const int kcp = s & 63;
        const int kcl = (kcp & 56) | ((kcp & 7) ^ (row & 7));
        gl_lds16(Ab + (r0 + row) * K + kcl * 8, &Alds[s * 8]);
    }

    f32x4 acc[2][2];
    #pragma unroll
    for (int rt = 0; rt < 2; ++rt)
        #pragma unroll
        for (int ct = 0; ct < 2; ++ct) acc[rt][ct] = (f32x4){0.f, 0.f, 0.f, 0.f};

    const ushort* __restrict__ Brow0 = Bb + (n0 + wc * 32 + m16) * K;
    const ushort* __restrict__ Brow1 = Brow0 + 16 * K;

    __syncthreads();    // single drain of the A stage

    #pragma unroll
    for (int ks = 0; ks < K; ks += 32) {
        const int kcq = (ks >> 3) + q;
        short8 av[2], bv[2];
        bv[0] = *(const short8*)&Brow0[ks + q * 8];
        bv[1] = *(const short8*)&Brow1[ks + q * 8];
        #pragma unroll
        for (int jj = 0; jj < 2; ++jj) {
            const int ar = wr * 32 + jj * 16 + m16;
            const int slot = (kcq & 56) | ((kcq & 7) ^ (ar & 7));
            av[jj] = *(const short8*)&Alds[ar * K + slot * 8];
        }
        #pragma unroll
        for (int rt = 0; rt < 2; ++rt)
            #pragma unroll
            for (int ct = 0; ct < 2; ++ct)
                acc[rt][ct] = __builtin_amdgcn_mfma_f32_16x16x32_bf16(
                    av[rt], bv[ct], acc[rt][ct], 0, 0, 0);
    }

    // epilogue: dist2 -> p = exp(g*exp(-dist)); store + deterministic partials
    const float g = 1.0f / (1.0f + __expf(-temp[0]));
    #pragma unroll
    for (int rt = 0; rt < 2; ++rt) {
        float s[4] = {0.f, 0.f, 0.f, 0.f};
        #pragma unroll
        for (int ct = 0; ct < 2; ++ct) {
            const int fcol = n0 + wc * 32 + ct * 16 + m16;
            const float cn = c[fcol];
            #pragma unroll
            for (int i = 0; i < 4; ++i) {
                const float dist2 = acc[rt][ct][i] + cn;
                const float dist = sqrtf(fmaxf(dist2, 0.0f));
                const float p = __expf(g * __expf(-dist));
                const int row = r0 + wr * 32 + rt * 16 + q * 4 + i;
                out[row * NF + fcol] = p;
                s[i] += p;
            }
        }
        #pragma unroll
        for (int i = 0; i < 4; ++i) {
            #pragma unroll
            for (int mask = 1; mask < 16; mask <<= 1)
                s[i] += __shfl_xor(s[i], mask, 64);
        }
        if (m16 == 0) {
            #pragma unroll
            for (int i = 0; i < 4; ++i) sums[w][rt * 16 + q * 4 + i] = s[i];
        }
    }
    __syncthreads();
    if (t < BM) {
        const int half = t >> 5, lr = t & 31;
        rowPartial[nc * BATCH + r0 + t] =
            sums[half * 2][lr] + sums[half * 2 + 1][lr];
    }
}

// ---------------------------------------------------------------------------
// K3: block = one batch row; normalize by the 16 chunk-sums.
__global__ __launch_bounds__(256) void k_norm(float* __restrict__ out,
                                              const float* __restrict__ rowPartial) {
    const int row = blockIdx.x;
    float ssum = 0.0f;
    #pragma unroll
    for (int ch = 0; ch < NCHUNK; ++ch) ssum += rowPartial[ch * BATCH + row];
    const float inv = 1.0f / ssum;
    float4* o4 = (float4*)(out + row * NF);
    float4 v = o4[threadIdx.x];
    v.x *= inv; v.y *= inv; v.z *= inv; v.w *= inv;
    o4[threadIdx.x] = v;
}

extern "C" void kernel_launch(void* const* d_in, const int* in_sizes, int n_in,
                              void* d_out, int out_size, void* d_ws, size_t ws_size,
                              hipStream_t stream) {
    const float* x     = (const float*)d_in[0];
    const float* mu    = (const float*)d_in[1];
    const float* sigma = (const float*)d_in[2];
    const float* temp  = (const float*)d_in[3];
    float* out = (float*)d_out;

    char* ws = (char*)d_ws;
    ushort* Ab        = (ushort*)ws;
    ushort* Bb        = (ushort*)(ws + WS_B_OFF);
    float*  c         = (float*)(ws + WS_C_OFF);
    float*  rowPartial = (float*)(ws + WS_RP_OFF);

    k_prep<<<NF + BATCH * DIM / 256, 256, 0, stream>>>(mu, sigma, x,
                                                       (unsigned int*)Ab,
                                                       (unsigned int*)Bb, c);

    k_main<<<512, 256, 0, stream>>>(Ab, Bb, c, temp, out, rowPartial);

    k_norm<<<BATCH, 256, 0, stream>>>(out, rowPartial);
}